// Round 1
// baseline (332.889 us; speedup 1.0000x reference)
//
#include <hip/hip_runtime.h>
#include <hip/hip_bf16.h>
#include <math.h>

// Problem constants (from reference): N=524288 points, K=32 components, D=64 dims.
#define NPTS 524288
#define KC 32
#define DIM 64

// d_ws float layout:
//   [0 .. 4095]        AB table: float2 {A=-0.5/var, B=mu/var} per (k,d), k-major
//   [4096 .. 4127]     C[k] = log(pi) - 0.5*(sum mu^2/var + sum log var + D*log(2pi))
//   [4128 .. 4159]     dem[K]      (accumulators, zeroed each launch)
//   [4160 .. 6207]     rx[K][D]
//   [6208 .. 8255]     rx2[K][D]
#define WS_AB    0
#define WS_C     (2*KC*DIM)
#define WS_ACC   (WS_C + KC)
#define ACC_DEM  0
#define ACC_RX   KC
#define ACC_RX2  (KC + KC*DIM)

__global__ void gmm_prep(const float* __restrict__ mu, const float* __restrict__ var,
                         const float* __restrict__ pi, float* __restrict__ ws) {
    int t = threadIdx.x + blockIdx.x * blockDim.x;
    if (t < KC * DIM) {
        float v = var[t];
        float m = mu[t];
        float iv = 1.0f / v;
        ws[WS_AB + 2 * t]     = -0.5f * iv;   // A
        ws[WS_AB + 2 * t + 1] = m * iv;       // B
    }
    if (t < KC) {
        float s = 0.0f;
        const float LOG2PI = 1.8378770664093453f;
        for (int d = 0; d < DIM; ++d) {
            float v = var[t * DIM + d];
            float m = mu[t * DIM + d];
            s += m * m / v + logf(v);
        }
        ws[WS_C + t] = logf(pi[t]) - 0.5f * (s + DIM * LOG2PI);
    }
}

__global__ __launch_bounds__(256, 4)
void gmm_main(const float* __restrict__ X, const float* __restrict__ ws,
              float* __restrict__ acc) {
    __shared__ float rs[KC][256];   // r_s[k][p] : 32 KB, stride-1 writes, uniform reads

    const int tid  = threadIdx.x;
    const int lane = tid & 63;
    const int wv   = tid >> 6;      // 4 waves; wave wv owns k in [8wv, 8wv+8)

    // Per-wave register accumulators, live across all batches of this block.
    float demw[8], rxw[8], rx2w[8];
#pragma unroll
    for (int kk = 0; kk < 8; ++kk) { demw[kk] = 0.f; rxw[kk] = 0.f; rx2w[kk] = 0.f; }

    const float2* AB = (const float2*)(ws + WS_AB);
    const float*  Cv = ws + WS_C;

    const int step = gridDim.x * 256;
    for (int base = blockIdx.x * 256; base < NPTS; base += step) {
        // ---------------- phase 1: one point per thread -> r[k] ----------------
        float lp[KC];
#pragma unroll
        for (int k = 0; k < KC; ++k) lp[k] = Cv[k];   // uniform -> s_load

        const float4* xp4 = (const float4*)(X + (size_t)(base + tid) * DIM);
        for (int c = 0; c < 8; ++c) {                 // rolled chunk loop over d
            float4 a = xp4[2 * c];
            float4 b = xp4[2 * c + 1];
            float xv[8] = {a.x, a.y, a.z, a.w, b.x, b.y, b.z, b.w};
#pragma unroll
            for (int k = 0; k < KC; ++k) {
                const float2* abk = AB + k * DIM + c * 8;  // uniform address
#pragma unroll
                for (int dd = 0; dd < 8; ++dd) {
                    float2 p = abk[dd];
                    lp[k] = fmaf(fmaf(p.x, xv[dd], p.y), xv[dd], lp[k]);
                }
            }
        }

        // stable softmax over k (all in registers)
        float m = lp[0];
#pragma unroll
        for (int k = 1; k < KC; ++k) m = fmaxf(m, lp[k]);
        float l = 0.0f;
#pragma unroll
        for (int k = 0; k < KC; ++k) { lp[k] = __expf(lp[k] - m); l += lp[k]; }
        float inv = 1.0f / l;
#pragma unroll
        for (int k = 0; k < KC; ++k) rs[k][tid] = lp[k] * inv;

        __syncthreads();

        // ---------------- phase 2: wave wv accumulates its 8 k's, lane = d ------
        const int k0 = wv * 8;
        const float* xcol = X + (size_t)base * DIM + lane;
#pragma unroll 4
        for (int p = 0; p < 256; ++p) {
            float xv = xcol[(size_t)p * DIM];   // coalesced, L1/L2-hit
            float x2 = xv * xv;
#pragma unroll
            for (int kk = 0; kk < 8; ++kk) {
                float r = rs[k0 + kk][p];       // uniform LDS broadcast
                demw[kk] += r;
                rxw[kk]  = fmaf(r, xv, rxw[kk]);
                rx2w[kk] = fmaf(r, x2, rx2w[kk]);
            }
        }
        __syncthreads();   // rs reused next batch
    }

    // ---------------- epilogue: one atomicAdd per accumulated value ------------
#pragma unroll
    for (int kk = 0; kk < 8; ++kk) {
        int k = wv * 8 + kk;
        atomicAdd(&acc[ACC_RX  + k * DIM + lane], rxw[kk]);
        atomicAdd(&acc[ACC_RX2 + k * DIM + lane], rx2w[kk]);
        if (lane == 0) atomicAdd(&acc[ACC_DEM + k], demw[kk]);
    }
}

__global__ void gmm_finalize(const float* __restrict__ acc, float* __restrict__ out) {
    int t = threadIdx.x + blockIdx.x * blockDim.x;
    if (t >= KC * DIM) return;
    int k = t >> 6, d = t & 63;
    float dm  = acc[ACC_DEM + k];
    float iv  = 1.0f / dm;
    float rx  = acc[ACC_RX + t];
    float rx2 = acc[ACC_RX2 + t];
    float muv = rx * iv;
    float vav = rx2 * iv - muv * muv;   // == (rx2 - 2 mu rx + mu^2 dem)/dem
    out[k * 129 + 1 + d]  = muv;
    out[k * 129 + 65 + d] = vav;
    if (d == 0) out[k * 129] = dm * (1.0f / (float)NPTS);
}

extern "C" void kernel_launch(void* const* d_in, const int* in_sizes, int n_in,
                              void* d_out, int out_size, void* d_ws, size_t ws_size,
                              hipStream_t stream) {
    const float* X   = (const float*)d_in[0];
    const float* mu  = (const float*)d_in[1];
    const float* var = (const float*)d_in[2];
    const float* pi  = (const float*)d_in[3];
    float* ws  = (float*)d_ws;
    float* acc = ws + WS_ACC;
    float* out = (float*)d_out;

    // zero the accumulators every call (deterministic; graph-capture-safe)
    hipMemsetAsync(acc, 0, (KC + 2 * KC * DIM) * sizeof(float), stream);
    gmm_prep<<<8, 256, 0, stream>>>(mu, var, pi, ws);
    gmm_main<<<1024, 256, 0, stream>>>(X, ws, acc);
    gmm_finalize<<<8, 256, 0, stream>>>(acc, out);
}

// Round 2
// 63.951 us; speedup vs baseline: 5.2054x; 5.2054x over previous
//
#include <hip/hip_runtime.h>
#include <hip/hip_bf16.h>
#include <math.h>

#define NPTS 524288
#define KC 32
#define DIM 64
#define GRIDX 1024
#define ITERS 4   // GRIDX * 4 waves * 32 pts * ITERS == NPTS

typedef __attribute__((ext_vector_type(8)))  short short8v;
typedef __attribute__((ext_vector_type(16))) float f32x16;

// ws byte layout: W bf16[32][128] @0 (8192B) | C float[32] @8192 | acc float[4128] @8320
//   acc: [0..32) dem, [32..32+4096) rx-flat comp*128 + d2   (d2<64: x, d2>=64: x^2)
#define ACC_FLOATS (KC + KC * 128)

__device__ __forceinline__ short f2bf(float f) {
    unsigned u = __float_as_uint(f);
    unsigned r = (u + 0x7FFFu + ((u >> 16) & 1u)) >> 16;   // RNE
    return (short)r;
}

__global__ void gmm_prep(const float* __restrict__ mu, const float* __restrict__ var,
                         const float* __restrict__ pi, short* __restrict__ W,
                         float* __restrict__ C) {
    int t = threadIdx.x + blockIdx.x * blockDim.x;
    if (t < KC * 128) {
        int k = t >> 7, d = t & 127;
        float iv = 1.0f / var[k * DIM + (d & 63)];
        float v = (d < DIM) ? mu[k * DIM + d] * iv : -0.5f * iv;
        W[t] = f2bf(v);
    }
    if (t < KC) {
        const float LOG2PI = 1.8378770664093453f;
        float s = 0.0f;
        for (int d = 0; d < DIM; ++d) {
            float v = var[t * DIM + d];
            float m = mu[t * DIM + d];
            s += m * m / v + logf(v);
        }
        C[t] = logf(pi[t]) - 0.5f * (s + DIM * LOG2PI);
    }
}

// LDS: per-wave xtile [32 pts][272B] (bf16 x|x^2, 136 bf16/row) and r [32 comp][144B]
#define XT_ROW 272
#define XT_W   8704          // 32*272
#define RL_ROW 144
#define RL_W   4608          // 32*144
#define RL_BASE 34816        // 4*XT_W
#define SMEM_BYTES 53248     // >= RL_BASE + 4*RL_W = 53248 ; reduce scratch 3*64*68*4=52224 fits

__global__ __launch_bounds__(256, 2)
void gmm_main(const float* __restrict__ X, const short* __restrict__ W,
              const float* __restrict__ C, float* __restrict__ acc) {
    __shared__ unsigned char smem[SMEM_BYTES];
    __shared__ float demsc[4][KC];

    const int tid = threadIdx.x;
    const int l   = tid & 63;
    const int w   = tid >> 6;
    const int lm  = l & 31;       // MFMA row/col lane index
    const int lh  = l >> 5;       // k-chunk half

    unsigned char* xt = smem + w * XT_W;
    unsigned char* rl = smem + RL_BASE + w * RL_W;

    // Resident W fragments: A[m=comp=lm][k = ks*16 + lh*8 + j]
    short8v wf[8];
#pragma unroll
    for (int ks = 0; ks < 8; ++ks)
        wf[ks] = *(const short8v*)(W + lm * 128 + ks * 16 + lh * 8);

    // Per-lane C values in D-layout rows
    float cvec[16];
#pragma unroll
    for (int r = 0; r < 16; ++r) cvec[r] = C[(r & 3) + 8 * (r >> 2) + 4 * lh];

    f32x16 rxacc[4];
#pragma unroll
    for (int nt = 0; nt < 4; ++nt)
#pragma unroll
        for (int i = 0; i < 16; ++i) rxacc[nt][i] = 0.0f;
    float demacc[16];
#pragma unroll
    for (int r = 0; r < 16; ++r) demacc[r] = 0.0f;

    // prefetch iter 0: 32 pts * 64 f32 = 8KB, fully coalesced (1KB/inst)
    float4 xr[8];
    {
        const float* xs = X + (size_t)(((size_t)blockIdx.x * 4 + w) * 32) * DIM;
#pragma unroll
        for (int c = 0; c < 8; ++c) xr[c] = *(const float4*)(xs + c * 256 + l * 4);
    }

#pragma unroll 1
    for (int it = 0; it < ITERS; ++it) {
        // ---- stage regs -> LDS (bf16 x | x^2), wave-private, no barrier ----
#pragma unroll
        for (int c = 0; c < 8; ++c) {
            int p = c * 4 + (l >> 4);
            int dcol = (l & 15) * 4;
            float4 v = xr[c];
            short bx[4]  = { f2bf(v.x), f2bf(v.y), f2bf(v.z), f2bf(v.w) };
            short bx2[4] = { f2bf(v.x * v.x), f2bf(v.y * v.y),
                             f2bf(v.z * v.z), f2bf(v.w * v.w) };
            *(short4*)(xt + p * XT_ROW + dcol * 2)       = *(short4*)bx;
            *(short4*)(xt + p * XT_ROW + 128 + dcol * 2) = *(short4*)bx2;
        }
        // ---- prefetch next iter (overlaps all compute below) ----
        if (it < ITERS - 1) {
            const float* xs = X + (size_t)((((size_t)(it + 1) * GRIDX + blockIdx.x) * 4 + w) * 32) * DIM;
#pragma unroll
            for (int c = 0; c < 8; ++c) xr[c] = *(const float4*)(xs + c * 256 + l * 4);
        }

        // ---- GEMM-1: S[comp][pt] = C + sum_d W[comp][d] * xt[pt][d] ----
        f32x16 s;
#pragma unroll
        for (int r = 0; r < 16; ++r) s[r] = cvec[r];
#pragma unroll
        for (int ks = 0; ks < 8; ++ks) {
            short8v b = *(const short8v*)(xt + lm * XT_ROW + ks * 32 + lh * 16);
            s = __builtin_amdgcn_mfma_f32_32x32x16_bf16(wf[ks], b, s, 0, 0, 0);
        }

        // ---- softmax over 32 comps for col pt=lm (split across lane pair l, l^32) ----
        float m = s[0];
#pragma unroll
        for (int r = 1; r < 16; ++r) m = fmaxf(m, s[r]);
        m = fmaxf(m, __shfl_xor(m, 32, 64));
        float sum = 0.0f;
        float p[16];
#pragma unroll
        for (int r = 0; r < 16; ++r) { p[r] = __expf(s[r] - m); sum += p[r]; }
        sum += __shfl_xor(sum, 32, 64);
        float inv = 1.0f / sum;
#pragma unroll
        for (int r = 0; r < 16; ++r) {
            float rv = p[r] * inv;
            demacc[r] += rv;
            int comp = (r & 3) + 8 * (r >> 2) + 4 * lh;
            *(short*)(rl + comp * RL_ROW + lm * 2) = f2bf(rv);
        }

        // ---- GEMM-2: rx[comp][d2] += sum_n r[comp][n] * xt[n][d2] ----
#pragma unroll
        for (int ks = 0; ks < 2; ++ks) {
            short8v af = *(const short8v*)(rl + lm * RL_ROW + ks * 32 + lh * 16);
#pragma unroll
            for (int nt = 0; nt < 4; ++nt) {
                int d2 = nt * 32 + lm;
                short8v bv;
#pragma unroll
                for (int j = 0; j < 8; ++j)
                    bv[j] = *(const short*)(xt + (ks * 16 + lh * 8 + j) * XT_ROW + d2 * 2);
                rxacc[nt] = __builtin_amdgcn_mfma_f32_32x32x16_bf16(af, bv, rxacc[nt], 0, 0, 0);
            }
        }
    }

    // ---- dem: reduce over cols (lanes within 32-group), stash per wave ----
#pragma unroll
    for (int r = 0; r < 16; ++r) {
        float v = demacc[r];
        v += __shfl_xor(v, 1, 64);  v += __shfl_xor(v, 2, 64);
        v += __shfl_xor(v, 4, 64);  v += __shfl_xor(v, 8, 64);
        v += __shfl_xor(v, 16, 64);
        demacc[r] = v;
    }
    if (lm == 0) {
#pragma unroll
        for (int r = 0; r < 16; ++r)
            demsc[w][(r & 3) + 8 * (r >> 2) + 4 * lh] = demacc[r];
    }

    // ---- block reduce rx partials through LDS (reuse xtile space), then atomics ----
    __syncthreads();
    float* sc = (float*)smem;
    if (w > 0) {
        float* dst = sc + (size_t)(w - 1) * 4352 + (size_t)l * 68;
#pragma unroll
        for (int nt = 0; nt < 4; ++nt)
#pragma unroll
            for (int q = 0; q < 4; ++q) {
                float4 t4 = { rxacc[nt][q * 4 + 0], rxacc[nt][q * 4 + 1],
                              rxacc[nt][q * 4 + 2], rxacc[nt][q * 4 + 3] };
                *(float4*)(dst + nt * 16 + q * 4) = t4;
            }
    }
    __syncthreads();
    if (w == 0) {
#pragma unroll
        for (int nt = 0; nt < 4; ++nt)
#pragma unroll
            for (int r = 0; r < 16; ++r) {
                float v = rxacc[nt][r]
                        + sc[0 * 4352 + l * 68 + nt * 16 + r]
                        + sc[1 * 4352 + l * 68 + nt * 16 + r]
                        + sc[2 * 4352 + l * 68 + nt * 16 + r];
                int comp = (r & 3) + 8 * (r >> 2) + 4 * lh;
                int d2 = nt * 32 + lm;
                atomicAdd(&acc[KC + comp * 128 + d2], v);
            }
        if (l < KC) {
            float dv = demsc[0][l] + demsc[1][l] + demsc[2][l] + demsc[3][l];
            atomicAdd(&acc[l], dv);
        }
    }
}

__global__ void gmm_finalize(const float* __restrict__ acc, float* __restrict__ out) {
    int t = threadIdx.x + blockIdx.x * blockDim.x;
    if (t >= KC * DIM) return;
    int k = t >> 6, d = t & 63;
    float dm  = acc[k];
    float iv  = 1.0f / dm;
    float rx  = acc[KC + k * 128 + d];
    float rx2 = acc[KC + k * 128 + 64 + d];
    float muv = rx * iv;
    float vav = rx2 * iv - muv * muv;
    out[k * 129 + 1 + d]  = muv;
    out[k * 129 + 65 + d] = vav;
    if (d == 0) out[k * 129] = dm * (1.0f / (float)NPTS);
}

extern "C" void kernel_launch(void* const* d_in, const int* in_sizes, int n_in,
                              void* d_out, int out_size, void* d_ws, size_t ws_size,
                              hipStream_t stream) {
    const float* X   = (const float*)d_in[0];
    const float* mu  = (const float*)d_in[1];
    const float* var = (const float*)d_in[2];
    const float* pi  = (const float*)d_in[3];

    short* W   = (short*)d_ws;
    float* C   = (float*)((char*)d_ws + 8192);
    float* acc = (float*)((char*)d_ws + 8320);
    float* out = (float*)d_out;

    hipMemsetAsync(acc, 0, ACC_FLOATS * sizeof(float), stream);
    gmm_prep<<<16, 256, 0, stream>>>(mu, var, pi, W, C);
    gmm_main<<<GRIDX, 256, 0, stream>>>(X, W, C, acc);
    gmm_finalize<<<8, 256, 0, stream>>>(acc, out);
}